// Round 6
// baseline (415.004 us; speedup 1.0000x reference)
//
#include <hip/hip_runtime.h>
#include <math.h>

#define SD 768
#define SB 16
#define SM 8
#define SS 2048
#define TOK_ROW 2049
#define NEG_INF (-__builtin_inff())

// ws layout (float offsets). Total ~1.1M floats = 4.5 MB.
// ptradS stat-major:
//   [0,12288)      sum accumulators (fadd, init 0)
//   [12288,24576)  max accumulators (uint-encoded, atomicMax, init 0x00000000)
//   [24576,36864)  min accumulators (uint-encoded, atomicMin, init 0xFFFFFFFF)
#define OFF_PTRADS  0          // 3*16*768
#define OFF_PLEARN  36864      // 16*6912 (merged: fadd init 0; clf: plain store)
#define OFF_LTOT    147456     // 16*8 (fadd init 0)
#define OFF_P1A     147584     // 18*12288
#define OFF_P1B     368768     // 54*12288
#define OFF_HA      1032320    // 12288
#define OFF_HB      1044608    // 12288

__device__ __forceinline__ int clen(int v) { return v < 1 ? 1 : (v > SS ? SS : v); }

// order-preserving float<->uint encoding: f1 < f2  <=>  fenc(f1) < fenc(f2) (unsigned)
__device__ __forceinline__ unsigned fenc(float f) {
  unsigned u = __float_as_uint(f);
  return (u & 0x80000000u) ? ~u : (u ^ 0x80000000u);
}
__device__ __forceinline__ float fdec(unsigned u) {
  unsigned i = (u & 0x80000000u) ? (u ^ 0x80000000u) : ~u;
  return __uint_as_float(i);
}

// ============ init: accumulator identities + bias into out ====================
__global__ void k_init(float* __restrict__ ws, float* __restrict__ out,
                       const float* __restrict__ b2a, const float* __restrict__ b2b) {
  int i = blockIdx.x * 256 + threadIdx.x;
  int stride = gridDim.x * 256;
  for (int t = i; t < 147584; t += stride) {
    unsigned v = (t >= 24576 && t < 36864) ? 0xFFFFFFFFu : 0u;
    ((unsigned*)ws)[t] = v;
  }
  for (int t = i; t < 24576; t += stride) {
    int b = t / 1536, r = t - b * 1536;
    out[t] = (r < 768) ? b2a[r] : b2b[r - 768];
  }
}

// ============ K_pool: COLUMN-parallel pool reduce (sum/max/min) ===============
// grid (16 s-chunks of 128 rows, 16 b), 192 thr = 3 waves. Lane owns 4 channels
// (float4 at d=tid*4); serial loop over rows, coalesced 3KB/row. No shuffles,
// no LDS; accumulators in 12 regs; one fenc-encoded atomic merge per block.
__global__ __launch_bounds__(192) void k_pool(
    const float* __restrict__ tokens, const int* __restrict__ lengths,
    float* __restrict__ ptradS) {
  int sc = blockIdx.x, b = blockIdx.y;
  int len = clen(lengths[b]);
  int r0 = sc * 128;
  if (r0 >= len) return;
  int cnt = len - r0; if (cnt > 128) cnt = 128;
  int tid = threadIdx.x;
  const float* xp = tokens + ((size_t)b * TOK_ROW + 1 + r0) * SD + tid * 4;

  float4 s = make_float4(0.f, 0.f, 0.f, 0.f);
  float4 mx = make_float4(NEG_INF, NEG_INF, NEG_INF, NEG_INF);
  float4 mn = make_float4(-NEG_INF, -NEG_INF, -NEG_INF, -NEG_INF);

  float4 nv = *(const float4*)xp;
  for (int i = 0; i < cnt; ++i) {
    float4 v = nv;
    if (i + 1 < cnt) nv = *(const float4*)(xp + (size_t)(i + 1) * SD);
    s.x += v.x; s.y += v.y; s.z += v.z; s.w += v.w;
    mx.x = fmaxf(mx.x, v.x); mx.y = fmaxf(mx.y, v.y);
    mx.z = fmaxf(mx.z, v.z); mx.w = fmaxf(mx.w, v.w);
    mn.x = fminf(mn.x, v.x); mn.y = fminf(mn.y, v.y);
    mn.z = fminf(mn.z, v.z); mn.w = fminf(mn.w, v.w);
  }
  int ch = b * 768 + tid * 4;
  atomicAdd(&ptradS[ch    ], s.x);
  atomicAdd(&ptradS[ch + 1], s.y);
  atomicAdd(&ptradS[ch + 2], s.z);
  atomicAdd(&ptradS[ch + 3], s.w);
  unsigned* pmx = (unsigned*)&ptradS[12288 + ch];
  atomicMax(pmx,     fenc(mx.x)); atomicMax(pmx + 1, fenc(mx.y));
  atomicMax(pmx + 2, fenc(mx.z)); atomicMax(pmx + 3, fenc(mx.w));
  unsigned* pmn = (unsigned*)&ptradS[24576 + ch];
  atomicMin(pmn,     fenc(mn.x)); atomicMin(pmn + 1, fenc(mn.y));
  atomicMin(pmn + 2, fenc(mn.z)); atomicMin(pmn + 3, fenc(mn.w));
}

// ============ K_score: LN + scores + exp + O_c, 8 waves x 8 rows =============
// grid (32 chunks of 64 rows, 16 b), 512 thr = 8 waves; wave w owns rows
// [c*64+8w,+8). Only ~1 working block/CU (work-capped), so parallelism goes
// INSIDE the block: 8 waves/CU = 2/SIMD, serial rows halved vs 4-wave version.
// q: m=0..3 in VGPRs, m=4..7 in LDS. LN mu/rstd via s1/s2 shuffle rails.
// Cross-wave O merge via LDS atomicAdd (no serial r-loop).
// Softmax fixed reference m=0 (exact: shift-invariant, scores ~N(0,0.02^2)).
__global__ __launch_bounds__(512, 2) void k_score(
    const float* __restrict__ tokens, const int* __restrict__ lengths,
    const float* __restrict__ q, const float* __restrict__ lns,
    const float* __restrict__ lnb,
    float* __restrict__ plearn, float* __restrict__ ltot) {
  int c = blockIdx.x, b = blockIdx.y;
  int len = clen(lengths[b]);
  int c0 = c * 64;
  if (c0 >= len) return;
  int tid = threadIdx.x, w = tid >> 6, lane = tid & 63;
  int mm2 = lane & 3;

  __shared__ float qs_lds[4][SD];         // 12 KB  qs for m=4..7
  __shared__ float p_lds[8][8][8];        // 2 KB   exp(scores)
  __shared__ float O_lds[SM][SD];         // 24 KB
  __shared__ float l_lds[8][8];

  // init p_lds to 0 (invalid rows contribute p=0)
  if (tid < 512) (&p_lds[0][0][0])[tid] = 0.f;

  // ---- q setup: m<4 -> qr regs; m>=4 -> qs_lds (wave 0 writes) ----
  float4 qr[4][3];
  float qs1A, qs1B, qbA, qbB;
  {
    float4 l4[3], lb4[3];
    #pragma unroll
    for (int g = 0; g < 3; ++g) {
      l4[g] = *(const float4*)(lns + g * 256 + lane * 4);
      lb4[g] = *(const float4*)(lnb + g * 256 + lane * 4);
    }
    float qs1r[8], qbr[8];
    #pragma unroll
    for (int m = 0; m < 8; ++m) {
      float s1 = 0.f, sb = 0.f;
      #pragma unroll
      for (int g = 0; g < 3; ++g) {
        float4 qv = *(const float4*)(q + m * SD + g * 256 + lane * 4);
        float4 qs;
        qs.x = qv.x * l4[g].x; qs.y = qv.y * l4[g].y;
        qs.z = qv.z * l4[g].z; qs.w = qv.w * l4[g].w;
        if (m < 4) qr[m][g] = qs;
        else if (w == 0) *(float4*)&qs_lds[m - 4][g * 256 + lane * 4] = qs;
        s1 += qs.x + qs.y + qs.z + qs.w;
        sb += qv.x * lb4[g].x + qv.y * lb4[g].y + qv.z * lb4[g].z + qv.w * lb4[g].w;
      }
      #pragma unroll
      for (int o = 32; o; o >>= 1) { s1 += __shfl_xor(s1, o, 64); sb += __shfl_xor(sb, o, 64); }
      qs1r[m] = s1; qbr[m] = sb;
    }
    qs1A = qs1r[0]; qbA = qbr[0]; qs1B = qs1r[4]; qbB = qbr[4];
    #pragma unroll
    for (int m = 1; m < 4; ++m) {
      qs1A = (mm2 == m) ? qs1r[m] : qs1A;
      qbA  = (mm2 == m) ? qbr[m]  : qbA;
      qs1B = (mm2 == m) ? qs1r[4 + m] : qs1B;
      qbB  = (mm2 == m) ? qbr[4 + m]  : qbB;
    }
  }
  __syncthreads();  // p_lds init + qs_lds staging visible

  // ---- phase 1: LN stats + scores -> exp (2-deep pipelined loads) ----
  int srow = c0 + w * 8;
  int smax = len - srow; if (smax > 8) smax = 8; if (smax < 0) smax = 0;
  const float* xrow = tokens + ((size_t)b * TOK_ROW + 1 + srow) * SD;
  float lA = 0.f, lB = 0.f;

  float4 nx0 = {}, nx1 = {}, nx2 = {};
  if (smax > 0) {
    nx0 = *(const float4*)(xrow + lane * 4);
    nx1 = *(const float4*)(xrow + 256 + lane * 4);
    nx2 = *(const float4*)(xrow + 512 + lane * 4);
  }
  for (int i = 0; i < smax; ++i) {
    float4 x0 = nx0, x1 = nx1, x2 = nx2;
    if (i + 1 < smax) {
      const float* xq = xrow + (size_t)(i + 1) * SD;
      nx0 = *(const float4*)(xq + lane * 4);
      nx1 = *(const float4*)(xq + 256 + lane * 4);
      nx2 = *(const float4*)(xq + 512 + lane * 4);
    }
    float xv[12] = {x0.x, x0.y, x0.z, x0.w, x1.x, x1.y, x1.z, x1.w,
                    x2.x, x2.y, x2.z, x2.w};
    float s1 = 0.f, s2 = 0.f;
    #pragma unroll
    for (int j = 0; j < 12; ++j) { float v = xv[j]; s1 += v; s2 += v * v; }
    float d[8];
    #pragma unroll
    for (int mq = 0; mq < 4; ++mq) {
      float4 a0 = qr[mq][0], a1 = qr[mq][1], a2 = qr[mq][2];
      d[mq] = a0.x * xv[0] + a0.y * xv[1] + a0.z * xv[2] + a0.w * xv[3]
            + a1.x * xv[4] + a1.y * xv[5] + a1.z * xv[6] + a1.w * xv[7]
            + a2.x * xv[8] + a2.y * xv[9] + a2.z * xv[10] + a2.w * xv[11];
    }
    #pragma unroll
    for (int mq = 0; mq < 4; ++mq) {
      float acc = 0.f;
      #pragma unroll
      for (int g = 0; g < 3; ++g) {
        float4 qv = *(const float4*)&qs_lds[mq][g * 256 + lane * 4];
        acc += qv.x * xv[g*4] + qv.y * xv[g*4+1] + qv.z * xv[g*4+2] + qv.w * xv[g*4+3];
      }
      d[4 + mq] = acc;
    }
    // quad butterfly {1,2} on d; select A/B by lane&3; {4..32} on uA,uB,s1,s2;
    // finish s1,s2 with {1,2}
    #pragma unroll
    for (int o = 1; o <= 2; o <<= 1)
      #pragma unroll
      for (int m = 0; m < 8; ++m) d[m] += __shfl_xor(d[m], o, 64);
    float uA = d[0], uB = d[4];
    #pragma unroll
    for (int m = 1; m < 4; ++m) {
      uA = (mm2 == m) ? d[m] : uA;
      uB = (mm2 == m) ? d[4 + m] : uB;
    }
    #pragma unroll
    for (int o = 4; o <= 32; o <<= 1) {
      uA += __shfl_xor(uA, o, 64);
      uB += __shfl_xor(uB, o, 64);
      s1 += __shfl_xor(s1, o, 64);
      s2 += __shfl_xor(s2, o, 64);
    }
    #pragma unroll
    for (int o = 1; o <= 2; o <<= 1) { s1 += __shfl_xor(s1, o, 64); s2 += __shfl_xor(s2, o, 64); }
    float mu = s1 * (1.f / 768.f);
    float var = s2 * (1.f / 768.f) - mu * mu;
    float rstd = rsqrtf(var + 1e-5f);
    float peA = __expf((rstd * uA - rstd * mu * qs1A + qbA) * 0.03608439182435161f);
    float peB = __expf((rstd * uB - rstd * mu * qs1B + qbB) * 0.03608439182435161f);
    lA += peA; lB += peB;
    if (lane < 4) { p_lds[w][i][lane] = peA; p_lds[w][i][4 + lane] = peB; }
  }
  if (lane < 4) { l_lds[w][lane] = lA; l_lds[w][4 + lane] = lB; }
  __syncthreads();

  if (tid < 8) {
    float lt = 0.f;
    #pragma unroll
    for (int ww = 0; ww < 8; ++ww) lt += l_lds[ww][tid];
    atomicAdd(&ltot[b * 8 + tid], lt);
  }
  // zero O_lds for LDS-atomic merge
  {
    float* of = &O_lds[0][0];
    for (int j = tid; j < 6144; j += 512) of[j] = 0.f;
  }
  __syncthreads();

  // ---- phase 2: O (two m-halves; x re-read L2-hot; LDS-atomic cross-wave merge) ----
  #pragma unroll
  for (int half = 0; half < 2; ++half) {
    float O[4][12];
    #pragma unroll
    for (int mq = 0; mq < 4; ++mq)
      #pragma unroll
      for (int j = 0; j < 12; ++j) O[mq][j] = 0.f;
    float4 a0v = {}, a1v = {}, a2v = {}, b0v = {}, b1v = {}, b2v = {};
    if (smax > 0) {
      a0v = *(const float4*)(xrow + lane * 4);
      a1v = *(const float4*)(xrow + 256 + lane * 4);
      a2v = *(const float4*)(xrow + 512 + lane * 4);
    }
    if (smax > 1) {
      const float* xq = xrow + SD;
      b0v = *(const float4*)(xq + lane * 4);
      b1v = *(const float4*)(xq + 256 + lane * 4);
      b2v = *(const float4*)(xq + 512 + lane * 4);
    }
    for (int i = 0; i < smax; ++i) {
      float4 x0 = a0v, x1 = a1v, x2 = a2v;
      a0v = b0v; a1v = b1v; a2v = b2v;
      if (i + 2 < smax) {
        const float* xq = xrow + (size_t)(i + 2) * SD;
        b0v = *(const float4*)(xq + lane * 4);
        b1v = *(const float4*)(xq + 256 + lane * 4);
        b2v = *(const float4*)(xq + 512 + lane * 4);
      }
      float xv[12] = {x0.x, x0.y, x0.z, x0.w, x1.x, x1.y, x1.z, x1.w,
                      x2.x, x2.y, x2.z, x2.w};
      float4 pa = *(const float4*)&p_lds[w][i][half * 4];
      float pm[4] = {pa.x, pa.y, pa.z, pa.w};
      #pragma unroll
      for (int mq = 0; mq < 4; ++mq)
        #pragma unroll
        for (int j = 0; j < 12; ++j) O[mq][j] += pm[mq] * xv[j];
    }
    #pragma unroll
    for (int mq = 0; mq < 4; ++mq)
      #pragma unroll
      for (int g = 0; g < 3; ++g) {
        int dd = g * 256 + lane * 4;
        atomicAdd(&O_lds[half * 4 + mq][dd    ], O[mq][g*4]);
        atomicAdd(&O_lds[half * 4 + mq][dd + 1], O[mq][g*4+1]);
        atomicAdd(&O_lds[half * 4 + mq][dd + 2], O[mq][g*4+2]);
        atomicAdd(&O_lds[half * 4 + mq][dd + 3], O[mq][g*4+3]);
      }
  }
  __syncthreads();

  // ---- atomic writeout: O -> plearn (fadd); clf passthrough ----
  {
    const float* of = &O_lds[0][0];
    for (int j = tid; j < 6144; j += 512)
      atomicAdd(&plearn[(size_t)b * 6912 + j], of[j]);
  }
  if (c == 0)
    for (int dd = tid; dd < 768; dd += 512)
      plearn[(size_t)b * 6912 + 6144 + dd] = tokens[(size_t)b * TOK_ROW * SD + dd];
}

// ============ split-K GEMM partial: (16 x K) @ (K x 768), k-tile = 128 ========
// mode 0: X = ptradS (stat-major, decode/normalize at staging; uniform per block)
// mode 1: X = plearn (merged cols x 1/ltot; clf raw; uniform per block)
// mode 2: X = plain row-major [16][K]
// epi  0: write partials to P[(kt*16+b2)*768 + n]
// epi  1: atomicAdd into P[b2*1536 + n] (out pre-initialized with bias)
__global__ __launch_bounds__(256) void gemm_partial(
    const float* __restrict__ XA, const float* __restrict__ WA, int ktA, float* __restrict__ PA,
    const float* __restrict__ XB, const float* __restrict__ WB, float* __restrict__ PB,
    const int* __restrict__ lengths, const float* __restrict__ ltot,
    int modeA, int modeB, int epi) {
  int nt = blockIdx.x, ky = blockIdx.y;
  const float *X, *W; float* P; int kt, ktN, mode;
  if (ky < ktA) { X = XA; W = WA; P = PA; kt = ky; ktN = ktA; mode = modeA; }
  else { X = XB; W = WB; P = PB; kt = ky - ktA; ktN = gridDim.y - ktA; mode = modeB; }
  int K = ktN * 128;
  int k0 = kt * 128;
  __shared__ __align__(16) float xt[128 * 20];
  __shared__ float red[4][64][17];
  int tid = threadIdx.x;
  int kk = tid & 127, half = tid >> 7;
  #pragma unroll
  for (int u = 0; u < 8; ++u) {
    int b2 = half * 8 + u;
    float f;
    if (mode == 0) {
      int s = kt / 6;                             // stat, uniform per block
      f = X[s * 12288 + b2 * 768 + (k0 - s * 768) + kk];
      if (s == 0) f = f / (float)clen(lengths[b2]);       // mean = sum/len
      else        f = fdec(__float_as_uint(f));           // decode max/min
    } else if (mode == 1) {
      f = X[b2 * 6912 + k0 + kk];
      if (kt < 48) f = f / ltot[b2 * 8 + (k0 / 768)];     // merged / l_total
    } else {
      f = X[b2 * K + k0 + kk];
    }
    xt[kk * 20 + b2] = f;
  }
  __syncthreads();
  int w = tid >> 6, lane = tid & 63;
  int n = nt * 64 + lane;
  float acc[16];
  #pragma unroll
  for (int b2 = 0; b2 < 16; ++b2) acc[b2] = 0.f;
  const float* Wp = W + (size_t)k0 * SD + n;
  #pragma unroll 8
  for (int kj = 0; kj < 32; ++kj) {
    int k = w + kj * 4;
    float wv = Wp[(size_t)k * SD];
    const float4* xr = reinterpret_cast<const float4*>(xt + k * 20);
    float4 a0 = xr[0], a1 = xr[1], a2 = xr[2], a3 = xr[3];
    acc[0] += wv * a0.x; acc[1] += wv * a0.y; acc[2] += wv * a0.z; acc[3] += wv * a0.w;
    acc[4] += wv * a1.x; acc[5] += wv * a1.y; acc[6] += wv * a1.z; acc[7] += wv * a1.w;
    acc[8] += wv * a2.x; acc[9] += wv * a2.y; acc[10] += wv * a2.z; acc[11] += wv * a2.w;
    acc[12] += wv * a3.x; acc[13] += wv * a3.y; acc[14] += wv * a3.z; acc[15] += wv * a3.w;
  }
  #pragma unroll
  for (int b2 = 0; b2 < 16; ++b2) red[w][lane][b2] = acc[b2];
  __syncthreads();
  for (int i = tid; i < 1024; i += 256) {
    int nn = i & 63, b2 = i >> 6;
    float r = red[0][nn][b2] + red[1][nn][b2] + red[2][nn][b2] + red[3][nn][b2];
    if (epi == 0) P[(size_t)(kt * 16 + b2) * SD + nt * 64 + nn] = r;
    else          atomicAdd(&P[b2 * 1536 + nt * 64 + nn], r);
  }
}

// ============ reduce + bias + exact GELU (compile-time trip counts) ===========
__global__ void gelu_reduce(const float* __restrict__ PA, const float* __restrict__ b1a,
                            float* __restrict__ HA, const float* __restrict__ PB,
                            const float* __restrict__ b1b, float* __restrict__ HB) {
  int y = blockIdx.y;
  int j = blockIdx.x * 256 + threadIdx.x;  // < 12288
  float r;
  if (y == 0) {
    r = b1a[j % SD];
    #pragma unroll
    for (int kt = 0; kt < 18; ++kt) r += PA[kt * 12288 + j];
    HA[j] = r * 0.5f * (1.f + erff(r * 0.70710678118654752f));
  } else {
    r = b1b[j % SD];
    #pragma unroll
    for (int kt = 0; kt < 54; ++kt) r += PB[kt * 12288 + j];
    HB[j] = r * 0.5f * (1.f + erff(r * 0.70710678118654752f));
  }
}

extern "C" void kernel_launch(void* const* d_in, const int* in_sizes, int n_in,
                              void* d_out, int out_size, void* d_ws, size_t ws_size,
                              hipStream_t stream) {
  const float* tokens = (const float*)d_in[0];
  const int* lengths  = (const int*)d_in[1];
  const float* q      = (const float*)d_in[2];
  const float* lns    = (const float*)d_in[3];
  const float* lnb    = (const float*)d_in[4];
  const float* w1a    = (const float*)d_in[5];
  const float* b1a    = (const float*)d_in[6];
  const float* w2a    = (const float*)d_in[7];
  const float* b2a    = (const float*)d_in[8];
  const float* w1b    = (const float*)d_in[9];
  const float* b1b    = (const float*)d_in[10];
  const float* w2b    = (const float*)d_in[11];
  const float* b2b    = (const float*)d_in[12];
  float* ws  = (float*)d_ws;
  float* out = (float*)d_out;

  float* ptradS = ws + OFF_PTRADS;
  float* plearn = ws + OFF_PLEARN;
  float* ltot   = ws + OFF_LTOT;
  float* p1a    = ws + OFF_P1A;
  float* p1b    = ws + OFF_P1B;
  float* ha     = ws + OFF_HA;
  float* hb     = ws + OFF_HB;

  k_init<<<dim3(128), 256, 0, stream>>>(ws, out, b2a, b2b);
  k_pool<<<dim3(16, 16), 192, 0, stream>>>(tokens, lengths, ptradS);
  k_score<<<dim3(32, 16), 512, 0, stream>>>(tokens, lengths, q, lns, lnb,
                                            plearn, ltot);
  gemm_partial<<<dim3(12, 72), 256, 0, stream>>>(ptradS, w1a, 18, p1a,
                                                 plearn, w1b, p1b,
                                                 lengths, ltot, 0, 1, 0);
  gelu_reduce<<<dim3(48, 2), 256, 0, stream>>>(p1a, b1a, ha, p1b, b1b, hb);
  gemm_partial<<<dim3(12, 12), 256, 0, stream>>>(ha, w2a, 6, out,
                                                 hb, w2b, out + 768,
                                                 lengths, ltot, 2, 2, 1);
}

// Round 7
// 239.120 us; speedup vs baseline: 1.7355x; 1.7355x over previous
//
#include <hip/hip_runtime.h>
#include <math.h>

#define SD 768
#define SB 16
#define SM 8
#define SS 2048
#define TOK_ROW 2049
#define NEG_INF (-__builtin_inff())

// ws layout (float offsets).
// ptradS stat-major:
//   [0,12288)      sum accumulators (fadd, init 0)
//   [12288,24576)  max accumulators (uint-encoded, atomicMax, init 0x00000000)
//   [24576,36864)  min accumulators (uint-encoded, atomicMin, init 0xFFFFFFFF)
#define OFF_PTRADS  0          // 3*16*768
#define OFF_PLEARN  36864      // 16*6912 (merged: fadd init 0; clf: plain store)
#define OFF_LTOT    147456     // 16*8 (fadd init 0)
#define OFF_P1A     147584     // 18*12288
#define OFF_P1B     368768     // 54*12288
#define OFF_HA      1032320    // 12288
#define OFF_HB      1044608    // 12288
#define OFF_CNT     1056896    // 1 int: work-stealing counter (init 0)

#define NITEM 512              // 16 b x 32 chunks of 64 rows

__device__ __forceinline__ int clen(int v) { return v < 1 ? 1 : (v > SS ? SS : v); }

// order-preserving float<->uint encoding: f1 < f2  <=>  fenc(f1) < fenc(f2) (unsigned)
__device__ __forceinline__ unsigned fenc(float f) {
  unsigned u = __float_as_uint(f);
  return (u & 0x80000000u) ? ~u : (u ^ 0x80000000u);
}
__device__ __forceinline__ float fdec(unsigned u) {
  unsigned i = (u & 0x80000000u) ? (u ^ 0x80000000u) : ~u;
  return __uint_as_float(i);
}

// ============ init: accumulator identities + bias into out + steal counter ====
__global__ void k_init(float* __restrict__ ws, float* __restrict__ out,
                       const float* __restrict__ b2a, const float* __restrict__ b2b) {
  int i = blockIdx.x * 256 + threadIdx.x;
  int stride = gridDim.x * 256;
  for (int t = i; t < 147584; t += stride) {
    unsigned v = (t >= 24576 && t < 36864) ? 0xFFFFFFFFu : 0u;
    ((unsigned*)ws)[t] = v;
  }
  for (int t = i; t < 24576; t += stride) {
    int b = t / 1536, r = t - b * 1536;
    out[t] = (r < 768) ? b2a[r] : b2b[r - 768];
  }
  if (i == 0) ((int*)ws)[OFF_CNT] = 0;
}

// ============ K_fused: pool + LN + scores + exp + O in ONE pass ==============
// 256 blocks (1/CU) x 512 thr = 8 waves. Work-stealing over NITEM=512 items
// (item = (b, 64-row chunk)); empty items skipped cheaply; all CUs stay busy
// until global work exhausted. Wave w owns rows [c*64+8w, +8) of its item.
// Per row: pool partials + LN stats + 8 score dots (q in LDS) -> one fused
// butterfly -> exp (fixed m=0 reference; exact by shift-invariance, scores
// ~N(0,0.02^2)) -> width-4 shuffle broadcast of the 8 probs -> O[8][12]
// accumulated inline (x read ONCE; no p_lds, no phase 2, no LDS atomics).
// Cross-wave: pool via wave-disjoint pool_lds; O via serial r-loop (R4 style).
// Cross-chunk: device atomics into ptradS/plearn/ltot (R4 scheme).
__global__ __launch_bounds__(512, 1) void k_fused(
    const float* __restrict__ tokens, const int* __restrict__ lengths,
    const float* __restrict__ q, const float* __restrict__ lns,
    const float* __restrict__ lnb, float* __restrict__ ptradS,
    float* __restrict__ plearn, float* __restrict__ ltot,
    int* __restrict__ cnt) {
  __shared__ float q_lds[8][SD];          // 24 KB  qs = q * ln_scale
  __shared__ float O_lds[SM][SD];         // 24 KB  cross-wave O merge
  __shared__ float pool_lds[8][3][SD];    // 72 KB  wave-disjoint pool partials
  __shared__ float l_lds[8][8];
  __shared__ float qmeta[16];             // qs1[8], qb[8]
  __shared__ int item_s;
  int tid = threadIdx.x, w = tid >> 6, lane = tid & 63;
  int mm2 = lane & 3;

  // ---- q setup: wave w owns m=w (8 waves = 8 queries) ----
  {
    float s1 = 0.f, sb = 0.f;
    #pragma unroll
    for (int g = 0; g < 3; ++g) {
      float4 l4  = *(const float4*)(lns + g * 256 + lane * 4);
      float4 lb4 = *(const float4*)(lnb + g * 256 + lane * 4);
      float4 qv  = *(const float4*)(q + w * SD + g * 256 + lane * 4);
      float4 qs = make_float4(qv.x * l4.x, qv.y * l4.y, qv.z * l4.z, qv.w * l4.w);
      *(float4*)&q_lds[w][g * 256 + lane * 4] = qs;
      s1 += qs.x + qs.y + qs.z + qs.w;
      sb += qv.x * lb4.x + qv.y * lb4.y + qv.z * lb4.z + qv.w * lb4.w;
    }
    #pragma unroll
    for (int o = 32; o; o >>= 1) { s1 += __shfl_xor(s1, o, 64); sb += __shfl_xor(sb, o, 64); }
    if (lane == 0) { qmeta[w] = s1; qmeta[8 + w] = sb; }
  }
  __syncthreads();
  float qs1A = qmeta[mm2],     qs1B = qmeta[4 + mm2];
  float qbA  = qmeta[8 + mm2], qbB  = qmeta[12 + mm2];
  const float KS = 0.03608439182435161f;   // 1/sqrt(768)

  for (;;) {
    __syncthreads();                       // LDS reuse guard
    if (tid == 0) item_s = atomicAdd(cnt, 1);
    __syncthreads();                       // publish item
    int item = item_s;
    if (item >= NITEM) break;
    int b = item >> 5, c = item & 31;
    int len = clen(lengths[b]);
    int c0 = c * 64;
    if (c0 >= len) continue;               // cheap skip (uniform)

    int srow = c0 + w * 8;
    int smax = len - srow; if (smax > 8) smax = 8; if (smax < 0) smax = 0;
    const float* xrow = tokens + ((size_t)b * TOK_ROW + 1 + srow) * SD;

    float psum[12], pmx[12], pmn[12];
    #pragma unroll
    for (int j = 0; j < 12; ++j) { psum[j] = 0.f; pmx[j] = NEG_INF; pmn[j] = -NEG_INF; }
    float O[8][12];
    #pragma unroll
    for (int m = 0; m < 8; ++m)
      #pragma unroll
      for (int j = 0; j < 12; ++j) O[m][j] = 0.f;
    float lA = 0.f, lB = 0.f;

    float4 nx0 = {}, nx1 = {}, nx2 = {};
    if (smax > 0) {
      nx0 = *(const float4*)(xrow + lane * 4);
      nx1 = *(const float4*)(xrow + 256 + lane * 4);
      nx2 = *(const float4*)(xrow + 512 + lane * 4);
    }
    for (int i = 0; i < smax; ++i) {
      float4 x0 = nx0, x1 = nx1, x2 = nx2;
      if (i + 1 < smax) {
        const float* xq = xrow + (size_t)(i + 1) * SD;
        nx0 = *(const float4*)(xq + lane * 4);
        nx1 = *(const float4*)(xq + 256 + lane * 4);
        nx2 = *(const float4*)(xq + 512 + lane * 4);
      }
      float xv[12] = {x0.x, x0.y, x0.z, x0.w, x1.x, x1.y, x1.z, x1.w,
                      x2.x, x2.y, x2.z, x2.w};
      float s1 = 0.f, s2 = 0.f;
      #pragma unroll
      for (int j = 0; j < 12; ++j) {
        float v = xv[j];
        psum[j] += v;
        pmx[j] = fmaxf(pmx[j], v);
        pmn[j] = fminf(pmn[j], v);
        s1 += v;
        s2 += v * v;
      }
      float d[8];
      #pragma unroll
      for (int m = 0; m < 8; ++m) {
        float4 q0 = *(const float4*)&q_lds[m][lane * 4];
        float4 q1 = *(const float4*)&q_lds[m][256 + lane * 4];
        float4 q2 = *(const float4*)&q_lds[m][512 + lane * 4];
        d[m] = q0.x * xv[0] + q0.y * xv[1] + q0.z * xv[2] + q0.w * xv[3]
             + q1.x * xv[4] + q1.y * xv[5] + q1.z * xv[6] + q1.w * xv[7]
             + q2.x * xv[8] + q2.y * xv[9] + q2.z * xv[10] + q2.w * xv[11];
      }
      // butterfly {1,2} on all 8 d; select A/B by lane&3; {4..32} with s1,s2;
      // finish s1,s2 with {1,2}
      #pragma unroll
      for (int o = 1; o <= 2; o <<= 1)
        #pragma unroll
        for (int m = 0; m < 8; ++m) d[m] += __shfl_xor(d[m], o, 64);
      float uA = d[0], uB = d[4];
      #pragma unroll
      for (int m = 1; m < 4; ++m) {
        uA = (mm2 == m) ? d[m] : uA;
        uB = (mm2 == m) ? d[4 + m] : uB;
      }
      #pragma unroll
      for (int o = 4; o <= 32; o <<= 1) {
        uA += __shfl_xor(uA, o, 64);
        uB += __shfl_xor(uB, o, 64);
        s1 += __shfl_xor(s1, o, 64);
        s2 += __shfl_xor(s2, o, 64);
      }
      #pragma unroll
      for (int o = 1; o <= 2; o <<= 1) { s1 += __shfl_xor(s1, o, 64); s2 += __shfl_xor(s2, o, 64); }
      float mu = s1 * (1.f / 768.f);
      float var = s2 * (1.f / 768.f) - mu * mu;
      float rstd = rsqrtf(var + 1e-5f);
      float peA = __expf((rstd * uA - rstd * mu * qs1A + qbA) * KS);
      float peB = __expf((rstd * uB - rstd * mu * qs1B + qbB) * KS);
      lA += peA; lB += peB;
      // broadcast all 8 probs to every lane (width-4 shuffles)
      float pm[8];
      #pragma unroll
      for (int m = 0; m < 4; ++m) {
        pm[m]     = __shfl(peA, m, 4);
        pm[4 + m] = __shfl(peB, m, 4);
      }
      #pragma unroll
      for (int m = 0; m < 8; ++m)
        #pragma unroll
        for (int j = 0; j < 12; ++j) O[m][j] += pm[m] * xv[j];
    }

    // l + pool partials -> LDS (wave-disjoint)
    if (lane < 4) { l_lds[w][lane] = lA; l_lds[w][4 + lane] = lB; }
    #pragma unroll
    for (int g = 0; g < 3; ++g) {
      int dd = g * 256 + lane * 4;
      *(float4*)&pool_lds[w][0][dd] = make_float4(psum[g*4], psum[g*4+1], psum[g*4+2], psum[g*4+3]);
      *(float4*)&pool_lds[w][1][dd] = make_float4(pmx[g*4], pmx[g*4+1], pmx[g*4+2], pmx[g*4+3]);
      *(float4*)&pool_lds[w][2][dd] = make_float4(pmn[g*4], pmn[g*4+1], pmn[g*4+2], pmn[g*4+3]);
    }
    __syncthreads();

    if (tid < 8) {
      float lt = 0.f;
      #pragma unroll
      for (int ww = 0; ww < 8; ++ww) lt += l_lds[ww][tid];
      atomicAdd(&ltot[b * 8 + tid], lt);
    }

    // cross-wave O merge: serial r-loop (non-atomic RMW, wave-exclusive)
    #pragma unroll
    for (int r = 0; r < 8; ++r) {
      if (w == r) {
        #pragma unroll
        for (int m = 0; m < 8; ++m)
          #pragma unroll
          for (int g = 0; g < 3; ++g) {
            int dd = g * 256 + lane * 4;
            float4 mine = make_float4(O[m][g*4], O[m][g*4+1], O[m][g*4+2], O[m][g*4+3]);
            if (r == 0) {
              *(float4*)&O_lds[m][dd] = mine;
            } else {
              float4 cur = *(float4*)&O_lds[m][dd];
              cur.x += mine.x; cur.y += mine.y; cur.z += mine.z; cur.w += mine.w;
              *(float4*)&O_lds[m][dd] = cur;
            }
          }
      }
      __syncthreads();
    }

    // writeout: O -> plearn (fadd); pool (8-way combine + encode) -> ptradS
    {
      const float* of = &O_lds[0][0];
      for (int j = tid; j < 6144; j += 512)
        atomicAdd(&plearn[(size_t)b * 6912 + j], of[j]);
    }
    for (int j = tid; j < 768; j += 512) {
      float s = 0.f, mx = NEG_INF, mn = -NEG_INF;
      #pragma unroll
      for (int ww = 0; ww < 8; ++ww) {
        s += pool_lds[ww][0][j];
        mx = fmaxf(mx, pool_lds[ww][1][j]);
        mn = fminf(mn, pool_lds[ww][2][j]);
      }
      atomicAdd(&ptradS[b * 768 + j], s);
      atomicMax((unsigned*)&ptradS[12288 + b * 768 + j], fenc(mx));
      atomicMin((unsigned*)&ptradS[24576 + b * 768 + j], fenc(mn));
    }
    if (c == 0)
      for (int dd = tid; dd < 768; dd += 512)
        plearn[(size_t)b * 6912 + 6144 + dd] = tokens[(size_t)b * TOK_ROW * SD + dd];
  }
}

// ============ split-K GEMM partial: (16 x K) @ (K x 768), k-tile = 128 ========
// mode 0: X = ptradS (stat-major, decode/normalize at staging; uniform per block)
// mode 1: X = plearn (merged cols x 1/ltot; clf raw; uniform per block)
// mode 2: X = plain row-major [16][K]
// epi  0: write partials to P[(kt*16+b2)*768 + n]
// epi  1: atomicAdd into P[b2*1536 + n] (out pre-initialized with bias)
__global__ __launch_bounds__(256) void gemm_partial(
    const float* __restrict__ XA, const float* __restrict__ WA, int ktA, float* __restrict__ PA,
    const float* __restrict__ XB, const float* __restrict__ WB, float* __restrict__ PB,
    const int* __restrict__ lengths, const float* __restrict__ ltot,
    int modeA, int modeB, int epi) {
  int nt = blockIdx.x, ky = blockIdx.y;
  const float *X, *W; float* P; int kt, ktN, mode;
  if (ky < ktA) { X = XA; W = WA; P = PA; kt = ky; ktN = ktA; mode = modeA; }
  else { X = XB; W = WB; P = PB; kt = ky - ktA; ktN = gridDim.y - ktA; mode = modeB; }
  int K = ktN * 128;
  int k0 = kt * 128;
  __shared__ __align__(16) float xt[128 * 20];
  __shared__ float red[4][64][17];
  int tid = threadIdx.x;
  int kk = tid & 127, half = tid >> 7;
  #pragma unroll
  for (int u = 0; u < 8; ++u) {
    int b2 = half * 8 + u;
    float f;
    if (mode == 0) {
      int s = kt / 6;                             // stat, uniform per block
      f = X[s * 12288 + b2 * 768 + (k0 - s * 768) + kk];
      if (s == 0) f = f / (float)clen(lengths[b2]);       // mean = sum/len
      else        f = fdec(__float_as_uint(f));           // decode max/min
    } else if (mode == 1) {
      f = X[b2 * 6912 + k0 + kk];
      if (kt < 48) f = f / ltot[b2 * 8 + (k0 / 768)];     // merged / l_total
    } else {
      f = X[b2 * K + k0 + kk];
    }
    xt[kk * 20 + b2] = f;
  }
  __syncthreads();
  int w = tid >> 6, lane = tid & 63;
  int n = nt * 64 + lane;
  float acc[16];
  #pragma unroll
  for (int b2 = 0; b2 < 16; ++b2) acc[b2] = 0.f;
  const float* Wp = W + (size_t)k0 * SD + n;
  #pragma unroll 8
  for (int kj = 0; kj < 32; ++kj) {
    int k = w + kj * 4;
    float wv = Wp[(size_t)k * SD];
    const float4* xr = reinterpret_cast<const float4*>(xt + k * 20);
    float4 a0 = xr[0], a1 = xr[1], a2 = xr[2], a3 = xr[3];
    acc[0] += wv * a0.x; acc[1] += wv * a0.y; acc[2] += wv * a0.z; acc[3] += wv * a0.w;
    acc[4] += wv * a1.x; acc[5] += wv * a1.y; acc[6] += wv * a1.z; acc[7] += wv * a1.w;
    acc[8] += wv * a2.x; acc[9] += wv * a2.y; acc[10] += wv * a2.z; acc[11] += wv * a2.w;
    acc[12] += wv * a3.x; acc[13] += wv * a3.y; acc[14] += wv * a3.z; acc[15] += wv * a3.w;
  }
  #pragma unroll
  for (int b2 = 0; b2 < 16; ++b2) red[w][lane][b2] = acc[b2];
  __syncthreads();
  for (int i = tid; i < 1024; i += 256) {
    int nn = i & 63, b2 = i >> 6;
    float r = red[0][nn][b2] + red[1][nn][b2] + red[2][nn][b2] + red[3][nn][b2];
    if (epi == 0) P[(size_t)(kt * 16 + b2) * SD + nt * 64 + nn] = r;
    else          atomicAdd(&P[b2 * 1536 + nt * 64 + nn], r);
  }
}

// ============ reduce + bias + exact GELU (compile-time trip counts) ===========
__global__ void gelu_reduce(const float* __restrict__ PA, const float* __restrict__ b1a,
                            float* __restrict__ HA, const float* __restrict__ PB,
                            const float* __restrict__ b1b, float* __restrict__ HB) {
  int y = blockIdx.y;
  int j = blockIdx.x * 256 + threadIdx.x;  // < 12288
  float r;
  if (y == 0) {
    r = b1a[j % SD];
    #pragma unroll
    for (int kt = 0; kt < 18; ++kt) r += PA[kt * 12288 + j];
    HA[j] = r * 0.5f * (1.f + erff(r * 0.70710678118654752f));
  } else {
    r = b1b[j % SD];
    #pragma unroll
    for (int kt = 0; kt < 54; ++kt) r += PB[kt * 12288 + j];
    HB[j] = r * 0.5f * (1.f + erff(r * 0.70710678118654752f));
  }
}

extern "C" void kernel_launch(void* const* d_in, const int* in_sizes, int n_in,
                              void* d_out, int out_size, void* d_ws, size_t ws_size,
                              hipStream_t stream) {
  const float* tokens = (const float*)d_in[0];
  const int* lengths  = (const int*)d_in[1];
  const float* q      = (const float*)d_in[2];
  const float* lns    = (const float*)d_in[3];
  const float* lnb    = (const float*)d_in[4];
  const float* w1a    = (const float*)d_in[5];
  const float* b1a    = (const float*)d_in[6];
  const float* w2a    = (const float*)d_in[7];
  const float* b2a    = (const float*)d_in[8];
  const float* w1b    = (const float*)d_in[9];
  const float* b1b    = (const float*)d_in[10];
  const float* w2b    = (const float*)d_in[11];
  const float* b2b    = (const float*)d_in[12];
  float* ws  = (float*)d_ws;
  float* out = (float*)d_out;

  float* ptradS = ws + OFF_PTRADS;
  float* plearn = ws + OFF_PLEARN;
  float* ltot   = ws + OFF_LTOT;
  float* p1a    = ws + OFF_P1A;
  float* p1b    = ws + OFF_P1B;
  float* ha     = ws + OFF_HA;
  float* hb     = ws + OFF_HB;
  int*   cnt    = (int*)(ws + OFF_CNT);

  k_init<<<dim3(128), 256, 0, stream>>>(ws, out, b2a, b2b);
  k_fused<<<dim3(256), 512, 0, stream>>>(tokens, lengths, q, lns, lnb,
                                         ptradS, plearn, ltot, cnt);
  gemm_partial<<<dim3(12, 72), 256, 0, stream>>>(ptradS, w1a, 18, p1a,
                                                 plearn, w1b, p1b,
                                                 lengths, ltot, 0, 1, 0);
  gelu_reduce<<<dim3(48, 2), 256, 0, stream>>>(p1a, b1a, ha, p1b, b1b, hb);
  gemm_partial<<<dim3(12, 12), 256, 0, stream>>>(ha, w2a, 6, out,
                                                 hb, w2b, out + 768,
                                                 lengths, ltot, 2, 2, 1);
}